// Round 5
// baseline (720.639 us; speedup 1.0000x reference)
//
#include <hip/hip_runtime.h>
#include <stdint.h>

#define C_IN 128
#define NUMD 524288
#define LNUMD 32768
#define NNUM_DM1 (LNUMD + NUMD/8)
#define PREFIX 16384
#define N_CONV (PREFIX + NNUM_DM1)   // 114688
#define N_EDGES (N_CONV * 7)         // 802816
#define ND8 (NUMD/8)                 // 65536
#define KCP 960                      // 7 blocks of 136 (128 ch + 7 onehot + 1 pad) + 8 pad
#define AGG_STRIDE 968

#define HIST_BLK (N_EDGES/256)               // 3136
#define COPY_BLK ((PREFIX+LNUMD)*32/256)     // 6144
#define PREPW_BLK ((128*KCP + 128*1024)/256) // 992
#define SCAT_BLK (N_EDGES/256)               // 3136
#define DOWN_BLK (ND8/64)                    // 1024

#define CONV_BLK 1024
#define CONV_ITER (N_CONV/16/CONV_BLK)       // 7
#define EBATCH 12

typedef __attribute__((ext_vector_type(8))) short short8;
typedef __attribute__((ext_vector_type(4))) float f32x4;

__device__ inline ushort f2b(float f){
  union { float f; uint32_t u; } v; v.f = f;
  uint32_t r = v.u + 0x7fffu + ((v.u >> 16) & 1u);
  return (ushort)(r >> 16);
}
__device__ inline float b2f_lo(uint32_t u){ union { uint32_t u; float f; } v; v.u = u << 16; return v.f; }
__device__ inline float b2f_hi(uint32_t u){ union { uint32_t u; float f; } v; v.u = u & 0xffff0000u; return v.f; }

// ---- fused: hist | copy prefix+leaf rows | weight conversion ----
__global__ void k_prep(const float* __restrict__ x, const float* __restrict__ wconv,
                       const float* __restrict__ wdown, const int* __restrict__ ei,
                       ushort* __restrict__ xconv, ushort* __restrict__ w16t,
                       ushort* __restrict__ wd16, int* __restrict__ cnt){
  const int bid = blockIdx.x;
  if (bid < HIST_BLK){
    int e = bid*256 + threadIdx.x;
    atomicAdd(&cnt[ei[e]], 1);
  } else if (bid < HIST_BLK + COPY_BLK){
    int gid = (bid - HIST_BLK)*256 + threadIdx.x;
    int row = gid >> 5, seg = (gid & 31) * 4;
    int srow, drow;
    if (row < PREFIX){ srow = row; drow = row; }
    else { int k = row - PREFIX; srow = PREFIX + k; drow = PREFIX + 3*k; }
    const float4 f = *(const float4*)(x + (size_t)srow*C_IN + seg);
    ushort4 o; o.x=f2b(f.x); o.y=f2b(f.y); o.z=f2b(f.z); o.w=f2b(f.w);
    *(ushort4*)(xconv + (size_t)drow*C_IN + seg) = o;
  } else {
    int gid = (bid - HIST_BLK - COPY_BLK)*256 + threadIdx.x;
    if (gid < 128*KCP){
      // padded layout: k = t*136 + c, c<135 -> wconv[t*135+c][o], else 0
      int o = gid / KCP, k = gid - o*KCP;
      float v = 0.f;
      if (k < 952){
        int t = k / 136, c = k - t*136;
        if (c < 135) v = wconv[(size_t)(t*135 + c)*128 + o];
      }
      w16t[gid] = f2b(v);
    } else {
      int i = gid - 128*KCP;
      wd16[i] = f2b(wdown[i]);
    }
  }
}

// ---- 3-stage coalesced scan of cnt[N_CONV] -> row_ptr + cursor ----
__global__ void k_scanA(const int* __restrict__ cnt, int* __restrict__ bsum){
  __shared__ int r[256];
  const int t = threadIdx.x, base = blockIdx.x*1024;
  int s = cnt[base+t] + cnt[base+t+256] + cnt[base+t+512] + cnt[base+t+768];
  r[t] = s; __syncthreads();
  for (int off=128; off>0; off>>=1){ if (t<off) r[t]+=r[t+off]; __syncthreads(); }
  if (t==0) bsum[blockIdx.x] = r[0];
}

__global__ void k_scanB(int* __restrict__ bsum){
  __shared__ int ps[128];
  const int t = threadIdx.x;
  int v = (t < 112) ? bsum[t] : 0;
  ps[t] = v; __syncthreads();
  for (int off=1; off<128; off<<=1){
    int val = ps[t];
    int add = (t>=off) ? ps[t-off] : 0;
    __syncthreads();
    ps[t] = val + add;
    __syncthreads();
  }
  int excl = (t==0) ? 0 : ps[t-1];
  if (t < 112) bsum[t] = excl;
}

__global__ void k_scanC(int* __restrict__ cnt, const int* __restrict__ bsum,
                        int* __restrict__ row_ptr){
  __shared__ int ps[256];
  const int b = blockIdx.x, t = threadIdx.x;
  int4 v = *(const int4*)(cnt + b*1024 + t*4);
  int s0 = v.x, s1 = s0+v.y, s2 = s1+v.z, s3 = s2+v.w;
  ps[t] = s3; __syncthreads();
  for (int off=1; off<256; off<<=1){
    int val = ps[t];
    int add = (t>=off) ? ps[t-off] : 0;
    __syncthreads();
    ps[t] = val + add;
    __syncthreads();
  }
  int excl = ((t==0) ? 0 : ps[t-1]) + bsum[b];
  int4 rp; rp.x = excl; rp.y = excl+s0; rp.z = excl+s1; rp.w = excl+s2;
  *(int4*)(row_ptr + b*1024 + t*4) = rp;
  *(int4*)(cnt + b*1024 + t*4) = rp;            // becomes cursor
  if (b == 111 && t == 255) row_ptr[N_CONV] = excl + s3;
}

// ---- fused: edge scatter (packed col|type|ntype) | down-projection GEMM ----
__global__ __launch_bounds__(256) void k_sd(const int* __restrict__ ei, const int* __restrict__ et,
    const int* __restrict__ ntype, int* __restrict__ cur, int* __restrict__ csp,
    const float* __restrict__ x, const ushort* __restrict__ wd16, ushort* __restrict__ xconv){
  const int bid = blockIdx.x;
  if (bid < SCAT_BLK){
    int e = bid*256 + threadIdx.x;
    int r = ei[e], c = ei[N_EDGES + e], t = et[e];
    int nt_ = ntype[c];
    int pos = atomicAdd(&cur[r], 1);
    csp[pos] = c | (t << 17) | (nt_ << 20);
    return;
  }
  __shared__ ushort at[64][56];
  const int tid = threadIdx.x;
  const int n0 = (bid - SCAT_BLK) * 64;
  const float* xd = x + (size_t)(PREFIX+LNUMD)*C_IN;
  const int wid = tid >> 6, l = tid & 63;
  const int arow = l & 15, kgrp = l >> 4;
  f32x4 acc[8];
  #pragma unroll
  for (int s=0;s<8;s++) acc[s] = (f32x4){0.f,0.f,0.f,0.f};
  const int srow = tid >> 2, kseg = (tid & 3) * 8;
  for (int k0 = 0; k0 < 1024; k0 += 32){
    __syncthreads();
    const float* src = xd + (size_t)(n0+srow)*1024 + k0 + kseg;
    float4 f0 = *(const float4*)src;
    float4 f1 = *(const float4*)(src+4);
    uint4 pk;
    pk.x = (uint)f2b(f0.x) | ((uint)f2b(f0.y)<<16);
    pk.y = (uint)f2b(f0.z) | ((uint)f2b(f0.w)<<16);
    pk.z = (uint)f2b(f1.x) | ((uint)f2b(f1.y)<<16);
    pk.w = (uint)f2b(f1.z) | ((uint)f2b(f1.w)<<16);
    *(uint4*)&at[srow][kseg] = pk;
    __syncthreads();
    short8 a = *(const short8*)&at[16*wid + arow][kgrp*8];
    #pragma unroll
    for (int s=0;s<8;s++){
      short8 b = *(const short8*)(wd16 + (size_t)(s*16 + arow)*1024 + k0 + kgrp*8);
      acc[s] = __builtin_amdgcn_mfma_f32_16x16x32_bf16(a, b, acc[s], 0,0,0);
    }
  }
  #pragma unroll
  for (int s=0;s<8;s++){
    int col = s*16 + arow;
    #pragma unroll
    for (int r=0;r<4;r++){
      int n = n0 + 16*wid + kgrp*4 + r;
      int i = 3*(n>>1) + 1 + (n&1);
      xconv[(size_t)(PREFIX + i)*C_IN + col] = f2b(acc[s][r]);
    }
  }
}

#define BAR_LGKM() do { \
    asm volatile("s_waitcnt lgkmcnt(0)" ::: "memory"); \
    __builtin_amdgcn_s_barrier(); \
    asm volatile("" ::: "memory"); \
  } while(0)

// ---- persistent pipelined aggregation + GEMM; raw barriers keep vmcnt in flight ----
// 1024 blocks x 512 threads: 16 slots x 32 lanes; 7 groups of 16 vertices per block.
__global__ __launch_bounds__(512, 6) void k_conv(const int* __restrict__ row_ptr,
    const int* __restrict__ csp, const ushort* __restrict__ xconv,
    const ushort* __restrict__ w16t, float* __restrict__ out){
  __shared__ ushort agg[16][AGG_STRIDE];
  const int tid = threadIdx.x;
  const int slot = tid >> 5, lane = tid & 31;

  // zero pad columns once (positions t*136+135 and 952..959; never written by dumps)
  if (tid < 256){
    int s = tid >> 4, q = tid & 15;
    agg[s][q < 7 ? q*136 + 135 : 945 + q] = 0;
  }

  int g = blockIdx.x;
  int e0c, e1c, e0n = 0, e1n = 0;
  {
    int v = g*16 + slot;
    e0c = row_ptr[v]; e1c = row_ptr[v+1];
    if (CONV_ITER > 1){
      int vn = v + CONV_BLK*16;
      e0n = row_ptr[vn]; e1n = row_ptr[vn+1];
    }
  }
  int meta_c[EBATCH], meta_n[EBATCH];
  uint2 d[EBATCH];
  int ncc = min(e1c - e0c, EBATCH), nn = 0;
  #pragma unroll
  for (int i=0;i<EBATCH;i++) if (i < ncc) meta_c[i] = csp[e0c + i];
  #pragma unroll
  for (int i=0;i<EBATCH;i++) if (i < ncc)
    d[i] = *(const uint2*)(xconv + (size_t)(meta_c[i] & 0x1FFFF)*C_IN + lane*4);

  for (int it = 0; it < CONV_ITER; ++it){
    const bool m1 = (it + 1 < CONV_ITER);
    const bool m2 = (it + 2 < CONV_ITER);
    int e0f = 0, e1f = 0;
    if (m2){
      int vf = (g + 2*CONV_BLK)*16 + slot;
      e0f = row_ptr[vf]; e1f = row_ptr[vf+1];
    }
    if (m1){
      nn = min(e1n - e0n, EBATCH);
      #pragma unroll
      for (int i=0;i<EBATCH;i++) if (i < nn) meta_n[i] = csp[e0n + i];
    }

    // ---- accumulate current group (d[] issued one full iteration ago) ----
    float a0[4],a1[4],a2[4],a3[4],a4[4],a5[4],a6[4];
    #pragma unroll
    for (int j=0;j<4;j++){ a0[j]=0;a1[j]=0;a2[j]=0;a3[j]=0;a4[j]=0;a5[j]=0;a6[j]=0; }
    float c0 = 0.f, c1 = 0.f;
    #define ACCUM(CP, DD) { \
      float f[4]; \
      f[0]=b2f_lo(DD.x); f[1]=b2f_hi(DD.x); \
      f[2]=b2f_lo(DD.y); f[3]=b2f_hi(DD.y); \
      int t_ = (CP >> 17) & 7; \
      switch(t_){ \
        case 0: { _Pragma("unroll") for(int j=0;j<4;j++) a0[j]+=f[j]; } break; \
        case 1: { _Pragma("unroll") for(int j=0;j<4;j++) a1[j]+=f[j]; } break; \
        case 2: { _Pragma("unroll") for(int j=0;j<4;j++) a2[j]+=f[j]; } break; \
        case 3: { _Pragma("unroll") for(int j=0;j<4;j++) a3[j]+=f[j]; } break; \
        case 4: { _Pragma("unroll") for(int j=0;j<4;j++) a4[j]+=f[j]; } break; \
        case 5: { _Pragma("unroll") for(int j=0;j<4;j++) a5[j]+=f[j]; } break; \
        default:{ _Pragma("unroll") for(int j=0;j<4;j++) a6[j]+=f[j]; } break; \
      } \
      int combo_ = t_*7 + ((CP >> 20) & 7); \
      c0 += (combo_ == lane) ? 1.f : 0.f; \
      c1 += (combo_ == lane + 32) ? 1.f : 0.f; \
    }
    #pragma unroll
    for (int i=0;i<EBATCH;i++) if (i < ncc) ACCUM(meta_c[i], d[i]);
    // remainder (deg > EBATCH), chunk-4
    for (int e = e0c + EBATCH; e < e1c; e += 4){
      int n4 = min(e1c - e, 4);
      int m4[4]; uint2 d4[4];
      #pragma unroll
      for (int i=0;i<4;i++) if (i < n4) m4[i] = csp[e + i];
      #pragma unroll
      for (int i=0;i<4;i++) if (i < n4)
        d4[i] = *(const uint2*)(xconv + (size_t)(m4[i] & 0x1FFFF)*C_IN + lane*4);
      #pragma unroll
      for (int i=0;i<4;i++) if (i < n4) ACCUM(m4[i], d4[i]);
    }
    #undef ACCUM

    // ---- dump acc -> LDS (packed b64 writes) ----
    #define DUMP(A,T) { uint2 pk; \
      pk.x = (uint)f2b(A[0]) | ((uint)f2b(A[1])<<16); \
      pk.y = (uint)f2b(A[2]) | ((uint)f2b(A[3])<<16); \
      *(uint2*)&agg[slot][T*136 + lane*4] = pk; }
    DUMP(a0,0) DUMP(a1,1) DUMP(a2,2) DUMP(a3,3) DUMP(a4,4) DUMP(a5,5) DUMP(a6,6)
    #undef DUMP
    agg[slot][(lane/7)*136 + 128 + (lane%7)] = f2b(c0);
    if (lane < 17) agg[slot][((lane+32)/7)*136 + 128 + ((lane+32)%7)] = f2b(c1);

    // ---- issue next group's gathers: fly across the GEMM (no vmcnt drain) ----
    if (m1){
      #pragma unroll
      for (int i=0;i<EBATCH;i++) if (i < nn)
        d[i] = *(const uint2*)(xconv + (size_t)(meta_n[i] & 0x1FFFF)*C_IN + lane*4);
    }

    BAR_LGKM();   // lgkmcnt(0) only: dump visible; gathers remain in flight

    // ---- GEMM: (16 x 960) @ (960 x 128); 8 waves, 16 cols each ----
    {
      const int wid = tid >> 6, l = tid & 63;
      const int arow = l & 15, kgrp = l >> 4;
      const int cb = wid * 16;
      f32x4 acc = {0.f,0.f,0.f,0.f};
      const ushort* wrow = w16t + (size_t)(cb + arow)*KCP + kgrp*8;
      #pragma unroll 6
      for (int k0 = 0; k0 < KCP; k0 += 32){
        short8 a = *(const short8*)&agg[arow][k0 + kgrp*8];
        short8 b = *(const short8*)(wrow + k0);
        acc = __builtin_amdgcn_mfma_f32_16x16x32_bf16(a, b, acc, 0,0,0);
      }
      #pragma unroll
      for (int r = 0; r < 4; r++)
        out[(size_t)(g*16 + kgrp*4 + r)*C_IN + cb + arow] = acc[r];
    }

    if (!m1) break;
    BAR_LGKM();   // own GEMM ds_reads done before next dump overwrites agg

    // rotate pipeline state
    e0c = e0n; e1c = e1n; e0n = e0f; e1n = e1f; ncc = nn;
    #pragma unroll
    for (int i=0;i<EBATCH;i++) meta_c[i] = meta_n[i];
    g += CONV_BLK;
  }
}

extern "C" void kernel_launch(void* const* d_in, const int* in_sizes, int n_in,
                              void* d_out, int out_size, void* d_ws, size_t ws_size,
                              hipStream_t stream){
  const float* x     = (const float*)d_in[0];
  const int*   ei    = (const int*)d_in[2];
  const int*   et    = (const int*)d_in[3];
  const int*   nt    = (const int*)d_in[4];
  const float* wdown = (const float*)d_in[5];
  const float* wconv = (const float*)d_in[6];
  float* out = (float*)d_out;

  char* p = (char*)d_ws;
  ushort* xconv = (ushort*)p; p += (size_t)N_CONV*C_IN*2;
  ushort* w16t  = (ushort*)p; p += (size_t)128*KCP*2;
  ushort* wd16  = (ushort*)p; p += (size_t)128*1024*2;
  int* cnt      = (int*)p;    p += (size_t)N_CONV*4;
  int* row_ptr  = (int*)p;    p += (size_t)(N_CONV+64)*4;
  int* bsum     = (int*)p;    p += 512;
  int* csp      = (int*)p;    p += (size_t)N_EDGES*4;

  hipMemsetAsync(cnt, 0, (size_t)N_CONV*4, stream);
  k_prep<<<HIST_BLK + COPY_BLK + PREPW_BLK, 256, 0, stream>>>(x, wconv, wdown, ei, xconv, w16t, wd16, cnt);
  k_scanA<<<112, 256, 0, stream>>>(cnt, bsum);
  k_scanB<<<1, 128, 0, stream>>>(bsum);
  k_scanC<<<112, 256, 0, stream>>>(cnt, bsum, row_ptr);
  k_sd<<<SCAT_BLK + DOWN_BLK, 256, 0, stream>>>(ei, et, nt, cnt, csp, x, wd16, xconv);
  k_conv<<<CONV_BLK, 512, 0, stream>>>(row_ptr, csp, xconv, w16t, out);
}

// Round 6
// 388.203 us; speedup vs baseline: 1.8563x; 1.8563x over previous
//
#include <hip/hip_runtime.h>
#include <stdint.h>

#define C_IN 128
#define NUMD 524288
#define LNUMD 32768
#define NNUM_DM1 (LNUMD + NUMD/8)
#define PREFIX 16384
#define N_CONV (PREFIX + NNUM_DM1)   // 114688
#define N_EDGES (N_CONV * 7)         // 802816
#define ND8 (NUMD/8)                 // 65536

#define HIST_BLK (N_EDGES/256)               // 3136
#define COPY_BLK ((PREFIX+LNUMD)*32/256)     // 6144
#define PREPW_N (114688 + 6272 + 131072)     // w16y + wbias + wd16 = 252032
#define PREPW_BLK ((PREPW_N + 255)/256)      // 985
#define SCAT_BLK (N_EDGES/256)               // 3136
#define DOWN_BLK (ND8/64)                    // 1024
#define EG 10

typedef __attribute__((ext_vector_type(8))) short short8;
typedef __attribute__((ext_vector_type(4))) float f32x4;

__device__ inline ushort f2b(float f){
  union { float f; uint32_t u; } v; v.f = f;
  uint32_t r = v.u + 0x7fffu + ((v.u >> 16) & 1u);
  return (ushort)(r >> 16);
}
__device__ inline float b2f_lo(uint32_t u){ union { uint32_t u; float f; } v; v.u = u << 16; return v.f; }
__device__ inline float b2f_hi(uint32_t u){ union { uint32_t u; float f; } v; v.u = u & 0xffff0000u; return v.f; }

// ---- fused: hist | copy prefix+leaf rows | weight conversion ----
__global__ void k_prep(const float* __restrict__ x, const float* __restrict__ wconv,
                       const float* __restrict__ wdown, const int* __restrict__ ei,
                       ushort* __restrict__ xconv, ushort* __restrict__ w16y,
                       ushort* __restrict__ wbias, ushort* __restrict__ wd16,
                       int* __restrict__ cnt){
  const int bid = blockIdx.x;
  if (bid < HIST_BLK){
    int e = bid*256 + threadIdx.x;
    atomicAdd(&cnt[ei[e]], 1);
  } else if (bid < HIST_BLK + COPY_BLK){
    int gid = (bid - HIST_BLK)*256 + threadIdx.x;
    int row = gid >> 5, seg = (gid & 31) * 4;
    int srow, drow;
    if (row < PREFIX){ srow = row; drow = row; }
    else { int k = row - PREFIX; srow = PREFIX + k; drow = PREFIX + 3*k; }
    const float4 f = *(const float4*)(x + (size_t)srow*C_IN + seg);
    ushort4 o; o.x=f2b(f.x); o.y=f2b(f.y); o.z=f2b(f.z); o.w=f2b(f.w);
    *(ushort4*)(xconv + (size_t)drow*C_IN + seg) = o;
  } else {
    int gid = (bid - HIST_BLK - COPY_BLK)*256 + threadIdx.x;
    if (gid < 114688){
      // w16y[t][o][k] = wconv[(t*135+k)*128 + o]
      int t = gid >> 14, rem = gid & 16383;
      int o = rem >> 7, k = rem & 127;
      w16y[gid] = f2b(wconv[(size_t)(t*135 + k)*128 + o]);
    } else if (gid < 120960){
      // wbias[t][n][o] = wconv[(t*135+128+n)*128 + o]
      int q = gid - 114688;
      int t = q / 896, rem = q % 896;
      int n = rem >> 7, o = rem & 127;
      wbias[q] = f2b(wconv[(size_t)(t*135 + 128 + n)*128 + o]);
    } else if (gid < PREPW_N){
      int i = gid - 120960;
      wd16[i] = f2b(wdown[i]);
    }
  }
}

// ---- 3-stage coalesced scan of cnt[N_CONV] -> row_ptr + cursor ----
__global__ void k_scanA(const int* __restrict__ cnt, int* __restrict__ bsum){
  __shared__ int r[256];
  const int t = threadIdx.x, base = blockIdx.x*1024;
  int s = cnt[base+t] + cnt[base+t+256] + cnt[base+t+512] + cnt[base+t+768];
  r[t] = s; __syncthreads();
  for (int off=128; off>0; off>>=1){ if (t<off) r[t]+=r[t+off]; __syncthreads(); }
  if (t==0) bsum[blockIdx.x] = r[0];
}

__global__ void k_scanB(int* __restrict__ bsum){
  __shared__ int ps[128];
  const int t = threadIdx.x;
  int v = (t < 112) ? bsum[t] : 0;
  ps[t] = v; __syncthreads();
  for (int off=1; off<128; off<<=1){
    int val = ps[t];
    int add = (t>=off) ? ps[t-off] : 0;
    __syncthreads();
    ps[t] = val + add;
    __syncthreads();
  }
  int excl = (t==0) ? 0 : ps[t-1];
  if (t < 112) bsum[t] = excl;
}

__global__ void k_scanC(int* __restrict__ cnt, const int* __restrict__ bsum,
                        int* __restrict__ row_ptr){
  __shared__ int ps[256];
  const int b = blockIdx.x, t = threadIdx.x;
  int4 v = *(const int4*)(cnt + b*1024 + t*4);
  int s0 = v.x, s1 = s0+v.y, s2 = s1+v.z, s3 = s2+v.w;
  ps[t] = s3; __syncthreads();
  for (int off=1; off<256; off<<=1){
    int val = ps[t];
    int add = (t>=off) ? ps[t-off] : 0;
    __syncthreads();
    ps[t] = val + add;
    __syncthreads();
  }
  int excl = ((t==0) ? 0 : ps[t-1]) + bsum[b];
  int4 rp; rp.x = excl; rp.y = excl+s0; rp.z = excl+s1; rp.w = excl+s2;
  *(int4*)(row_ptr + b*1024 + t*4) = rp;
  *(int4*)(cnt + b*1024 + t*4) = rp;            // becomes cursor
  if (b == 111 && t == 255) row_ptr[N_CONV] = excl + s3;
}

// ---- fused: edge scatter (csp = c*7+t = Y row) | down-projection GEMM ----
__global__ __launch_bounds__(256) void k_sd(const int* __restrict__ ei, const int* __restrict__ et,
    int* __restrict__ cur, int* __restrict__ csp,
    const float* __restrict__ x, const ushort* __restrict__ wd16, ushort* __restrict__ xconv){
  const int bid = blockIdx.x;
  if (bid < SCAT_BLK){
    int e = bid*256 + threadIdx.x;
    int r = ei[e], c = ei[N_EDGES + e], t = et[e];
    int pos = atomicAdd(&cur[r], 1);
    csp[pos] = c*7 + t;
    return;
  }
  __shared__ ushort at[64][56];
  const int tid = threadIdx.x;
  const int n0 = (bid - SCAT_BLK) * 64;
  const float* xd = x + (size_t)(PREFIX+LNUMD)*C_IN;
  const int wid = tid >> 6, l = tid & 63;
  const int arow = l & 15, kgrp = l >> 4;
  f32x4 acc[8];
  #pragma unroll
  for (int s=0;s<8;s++) acc[s] = (f32x4){0.f,0.f,0.f,0.f};
  const int srow = tid >> 2, kseg = (tid & 3) * 8;
  for (int k0 = 0; k0 < 1024; k0 += 32){
    __syncthreads();
    const float* src = xd + (size_t)(n0+srow)*1024 + k0 + kseg;
    float4 f0 = *(const float4*)src;
    float4 f1 = *(const float4*)(src+4);
    uint4 pk;
    pk.x = (uint)f2b(f0.x) | ((uint)f2b(f0.y)<<16);
    pk.y = (uint)f2b(f0.z) | ((uint)f2b(f0.w)<<16);
    pk.z = (uint)f2b(f1.x) | ((uint)f2b(f1.y)<<16);
    pk.w = (uint)f2b(f1.z) | ((uint)f2b(f1.w)<<16);
    *(uint4*)&at[srow][kseg] = pk;
    __syncthreads();
    short8 a = *(const short8*)&at[16*wid + arow][kgrp*8];
    #pragma unroll
    for (int s=0;s<8;s++){
      short8 b = *(const short8*)(wd16 + (size_t)(s*16 + arow)*1024 + k0 + kgrp*8);
      acc[s] = __builtin_amdgcn_mfma_f32_16x16x32_bf16(a, b, acc[s], 0,0,0);
    }
  }
  #pragma unroll
  for (int s=0;s<8;s++){
    int col = s*16 + arow;
    #pragma unroll
    for (int r=0;r<4;r++){
      int n = n0 + 16*wid + kgrp*4 + r;
      int i = 3*(n>>1) + 1 + (n&1);
      xconv[(size_t)(PREFIX + i)*C_IN + col] = f2b(acc[s][r]);
    }
  }
}

// ---- Y[c][t][o] = xconv[c] @ W_t[:128] + W_t[128+nt[c]]  (bf16 out) ----
// 896 blocks x 512 threads; per block: 128-row A tile (LDS, swizzled), 7 t's.
__global__ __launch_bounds__(512) void k_y(const ushort* __restrict__ xconv,
    const ushort* __restrict__ w16y, const ushort* __restrict__ wbias,
    const int* __restrict__ ntype, ushort* __restrict__ Y){
  __shared__ ushort As[128*128];    // row*128 + (c16 ^ (row&7))*8
  __shared__ ushort bsh[6272];
  __shared__ int nts[128];
  const int tid = threadIdx.x;
  const int tile = blockIdx.x;

  {
    int row = tid >> 2;
    int c0 = (tid & 3) * 4;
    const ushort* src = xconv + ((size_t)tile*128 + row)*128;
    #pragma unroll
    for (int i=0;i<4;i++){
      int c16 = c0 + i;
      uint4 v = *(const uint4*)(src + c16*8);
      *(uint4*)&As[row*128 + ((c16 ^ (row & 7))*8)] = v;
    }
  }
  for (int i = tid; i < 3136; i += 512) ((uint*)bsh)[i] = ((const uint*)wbias)[i];
  if (tid < 128) nts[tid] = ntype[tile*128 + tid];
  __syncthreads();

  const int w = tid >> 6, l = tid & 63;
  const int mg = w >> 2, nc = w & 3;          // 2 row-groups x 4 col-groups
  const int arow = l & 15, kgrp = l >> 4;
  const int obase = nc*32 + arow;

  for (int t = 0; t < 7; ++t){
    f32x4 acc[4][2];
    #pragma unroll
    for (int mf=0;mf<4;mf++){ acc[mf][0]=(f32x4){0,0,0,0}; acc[mf][1]=(f32x4){0,0,0,0}; }
    const ushort* wt = w16y + t*16384;
    #pragma unroll
    for (int kf = 0; kf < 4; ++kf){
      const int kof = kf*32 + kgrp*8;
      short8 b0 = *(const short8*)(wt + (size_t)obase*128 + kof);
      short8 b1 = *(const short8*)(wt + (size_t)(obase+16)*128 + kof);
      #pragma unroll
      for (int mf = 0; mf < 4; ++mf){
        int row = mg*64 + mf*16 + arow;
        int c16 = (kf*4 + kgrp) ^ (row & 7);
        short8 a = *(const short8*)&As[row*128 + c16*8];
        acc[mf][0] = __builtin_amdgcn_mfma_f32_16x16x32_bf16(a, b0, acc[mf][0], 0,0,0);
        acc[mf][1] = __builtin_amdgcn_mfma_f32_16x16x32_bf16(a, b1, acc[mf][1], 0,0,0);
      }
    }
    #pragma unroll
    for (int mf = 0; mf < 4; ++mf){
      #pragma unroll
      for (int j = 0; j < 4; ++j){
        int rl = mg*64 + mf*16 + (l>>4)*4 + j;
        int ntv = nts[rl];
        size_t grow = ((size_t)(tile*128 + rl)*7 + t)*128;
        int bb = (t*7 + ntv)*128;
        Y[grow + obase]      = f2b(acc[mf][0][j] + b2f_lo((uint)bsh[bb + obase]));
        Y[grow + obase + 16] = f2b(acc[mf][1][j] + b2f_lo((uint)bsh[bb + obase + 16]));
      }
    }
  }
}

// ---- out[v] = sum_e Y[csp[e]]  (pure gather-sum, f32 accum) ----
__global__ __launch_bounds__(256) void k_gather(const int* __restrict__ row_ptr,
    const int* __restrict__ csp, const ushort* __restrict__ Y, float* __restrict__ out){
  const int tid = threadIdx.x;
  const int slot = tid >> 5, lane = tid & 31;
  const int v = blockIdx.x*8 + slot;
  const int e0 = row_ptr[v], e1 = row_ptr[v+1];
  float acc[4] = {0.f, 0.f, 0.f, 0.f};

  int m[EG]; uint2 d[EG];
  const int n = min(e1 - e0, EG);
  #pragma unroll
  for (int i=0;i<EG;i++) if (i < n) m[i] = csp[e0 + i];
  #pragma unroll
  for (int i=0;i<EG;i++) if (i < n)
    d[i] = *(const uint2*)(Y + (size_t)m[i]*C_IN + lane*4);
  #pragma unroll
  for (int i=0;i<EG;i++){
    if (i < n){
      acc[0] += b2f_lo(d[i].x); acc[1] += b2f_hi(d[i].x);
      acc[2] += b2f_lo(d[i].y); acc[3] += b2f_hi(d[i].y);
    }
  }
  for (int e = e0 + EG; e < e1; e += 4){
    int n4 = min(e1 - e, 4);
    int m4[4]; uint2 d4[4];
    #pragma unroll
    for (int i=0;i<4;i++) if (i < n4) m4[i] = csp[e + i];
    #pragma unroll
    for (int i=0;i<4;i++) if (i < n4)
      d4[i] = *(const uint2*)(Y + (size_t)m4[i]*C_IN + lane*4);
    #pragma unroll
    for (int i=0;i<4;i++){
      if (i < n4){
        acc[0] += b2f_lo(d4[i].x); acc[1] += b2f_hi(d4[i].x);
        acc[2] += b2f_lo(d4[i].y); acc[3] += b2f_hi(d4[i].y);
      }
    }
  }
  float4 o; o.x = acc[0]; o.y = acc[1]; o.z = acc[2]; o.w = acc[3];
  *(float4*)(out + (size_t)v*C_IN + lane*4) = o;
}

extern "C" void kernel_launch(void* const* d_in, const int* in_sizes, int n_in,
                              void* d_out, int out_size, void* d_ws, size_t ws_size,
                              hipStream_t stream){
  const float* x     = (const float*)d_in[0];
  const int*   ei    = (const int*)d_in[2];
  const int*   et    = (const int*)d_in[3];
  const int*   nt    = (const int*)d_in[4];
  const float* wdown = (const float*)d_in[5];
  const float* wconv = (const float*)d_in[6];
  float* out = (float*)d_out;

  char* p = (char*)d_ws;
  ushort* xconv = (ushort*)p; p += (size_t)N_CONV*C_IN*2;        // 29.36 MB
  ushort* wd16  = (ushort*)p; p += (size_t)128*1024*2;           // 256 KB
  ushort* w16y  = (ushort*)p; p += (size_t)114688*2;             // 224 KB
  ushort* wbias = (ushort*)p; p += 16384;                        // 16 KB
  int* cnt      = (int*)p;    p += (size_t)N_CONV*4;             // 448 KB
  int* row_ptr  = (int*)p;    p += (size_t)(N_CONV+256)*4;
  int* bsum     = (int*)p;    p += 4096;
  int* csp      = (int*)p;    p += (size_t)N_EDGES*4;            // 3.2 MB
  ushort* Y     = (ushort*)p;                                    // 205.5 MB

  hipMemsetAsync(cnt, 0, (size_t)N_CONV*4, stream);
  k_prep<<<HIST_BLK + COPY_BLK + PREPW_BLK, 256, 0, stream>>>(x, wconv, wdown, ei, xconv, w16y, wbias, wd16, cnt);
  k_scanA<<<112, 256, 0, stream>>>(cnt, bsum);
  k_scanB<<<1, 128, 0, stream>>>(bsum);
  k_scanC<<<112, 256, 0, stream>>>(cnt, bsum, row_ptr);
  k_sd<<<SCAT_BLK + DOWN_BLK, 256, 0, stream>>>(ei, et, cnt, csp, x, wd16, xconv);
  k_y<<<N_CONV/128, 512, 0, stream>>>(xconv, w16y, wbias, nt, Y);
  k_gather<<<N_CONV/8, 256, 0, stream>>>(row_ptr, csp, Y, out);
}

// Round 7
// 363.227 us; speedup vs baseline: 1.9840x; 1.0688x over previous
//
#include <hip/hip_runtime.h>
#include <stdint.h>

#define C_IN 128
#define NUMD 524288
#define LNUMD 32768
#define NNUM_DM1 (LNUMD + NUMD/8)
#define PREFIX 16384
#define N_CONV (PREFIX + NNUM_DM1)   // 114688
#define N_EDGES (N_CONV * 7)         // 802816
#define ND8 (NUMD/8)                 // 65536
#define CAP 32
#define EG 12

#define COPY_BLK ((PREFIX+LNUMD)*32/256)     // 6144
#define PREPW_N (114688 + 6272 + 131072)     // w16y + wbias + wd16 = 252032
#define PREPW_BLK ((PREPW_N + 255)/256)      // 985
#define ZERO_BLK (N_CONV/1024)               // 112
#define SCAT_BLK (N_EDGES/256)               // 3136
#define DOWN_BLK (ND8/64)                    // 1024

typedef __attribute__((ext_vector_type(8))) short short8;
typedef __attribute__((ext_vector_type(4))) float f32x4;

__device__ inline ushort f2b(float f){
  union { float f; uint32_t u; } v; v.f = f;
  uint32_t r = v.u + 0x7fffu + ((v.u >> 16) & 1u);
  return (ushort)(r >> 16);
}
__device__ inline float b2f_lo(uint32_t u){ union { uint32_t u; float f; } v; v.u = u << 16; return v.f; }
__device__ inline float b2f_hi(uint32_t u){ union { uint32_t u; float f; } v; v.u = u & 0xffff0000u; return v.f; }

#define BAR_LGKM() do { \
    asm volatile("s_waitcnt lgkmcnt(0)" ::: "memory"); \
    __builtin_amdgcn_s_barrier(); \
    asm volatile("" ::: "memory"); \
  } while(0)

// ---- fused: copy prefix+leaf rows | weight conversion | zero cnt ----
__global__ void k_prep(const float* __restrict__ x, const float* __restrict__ wconv,
                       const float* __restrict__ wdown,
                       ushort* __restrict__ xconv, ushort* __restrict__ w16y,
                       ushort* __restrict__ wbias, ushort* __restrict__ wd16,
                       int* __restrict__ cnt){
  const int bid = blockIdx.x;
  if (bid < COPY_BLK){
    int gid = bid*256 + threadIdx.x;
    int row = gid >> 5, seg = (gid & 31) * 4;
    int srow, drow;
    if (row < PREFIX){ srow = row; drow = row; }
    else { int k = row - PREFIX; srow = PREFIX + k; drow = PREFIX + 3*k; }
    const float4 f = *(const float4*)(x + (size_t)srow*C_IN + seg);
    ushort4 o; o.x=f2b(f.x); o.y=f2b(f.y); o.z=f2b(f.z); o.w=f2b(f.w);
    *(ushort4*)(xconv + (size_t)drow*C_IN + seg) = o;
  } else if (bid < COPY_BLK + PREPW_BLK){
    int gid = (bid - COPY_BLK)*256 + threadIdx.x;
    if (gid < 114688){
      // w16y[t][o][k] = wconv[(t*135+k)*128 + o]
      int t = gid >> 14, rem = gid & 16383;
      int o = rem >> 7, k = rem & 127;
      w16y[gid] = f2b(wconv[(size_t)(t*135 + k)*128 + o]);
    } else if (gid < 120960){
      // wbias[t][n][o] = wconv[(t*135+128+n)*128 + o]
      int q = gid - 114688;
      int t = q / 896, rem = q % 896;
      int n = rem >> 7, o = rem & 127;
      wbias[q] = f2b(wconv[(size_t)(t*135 + 128 + n)*128 + o]);
    } else if (gid < PREPW_N){
      int i = gid - 120960;
      wd16[i] = f2b(wdown[i]);
    }
  } else {
    int gid = (bid - COPY_BLK - PREPW_BLK)*256 + threadIdx.x;
    int4 z = {0,0,0,0};
    *(int4*)(cnt + gid*4) = z;
  }
}

// ---- fused: edge scatter to fixed-cap buckets | down-projection GEMM (dbuf A) ----
__global__ __launch_bounds__(256) void k_sd(const int* __restrict__ ei, const int* __restrict__ et,
    int* __restrict__ cnt, int* __restrict__ bucket,
    const float* __restrict__ x, const ushort* __restrict__ wd16, ushort* __restrict__ xconv){
  const int bid = blockIdx.x;
  if (bid < SCAT_BLK){
    int e = bid*256 + threadIdx.x;
    int r = ei[e], c = ei[N_EDGES + e], t = et[e];
    int pos = atomicAdd(&cnt[r], 1);
    if (pos < CAP) bucket[r*CAP + pos] = c*7 + t;
    return;
  }
  __shared__ ushort As[2][64][32];
  const int tid = threadIdx.x;
  const int n0 = (bid - SCAT_BLK) * 64;
  const float* xd = x + (size_t)(PREFIX+LNUMD)*C_IN;
  const int wid = tid >> 6, l = tid & 63;
  const int arow = l & 15, kgrp = l >> 4;
  const int srow = tid >> 2, kseg = (tid & 3) * 8;
  const float* src = xd + (size_t)(n0+srow)*1024 + kseg;

  f32x4 acc[8];
  #pragma unroll
  for (int s=0;s<8;s++) acc[s] = (f32x4){0.f,0.f,0.f,0.f};

  float4 fa = *(const float4*)(src);
  float4 fb = *(const float4*)(src + 4);
  int cur = 0;
  for (int k0 = 0; k0 < 1024; k0 += 32){
    uint4 pk;
    pk.x = (uint)f2b(fa.x) | ((uint)f2b(fa.y)<<16);
    pk.y = (uint)f2b(fa.z) | ((uint)f2b(fa.w)<<16);
    pk.z = (uint)f2b(fb.x) | ((uint)f2b(fb.y)<<16);
    pk.w = (uint)f2b(fb.z) | ((uint)f2b(fb.w)<<16);
    *(uint4*)&As[cur][srow][kseg] = pk;
    if (k0 < 992){                       // prefetch k+1: stays in vmcnt across barrier
      fa = *(const float4*)(src + k0 + 32);
      fb = *(const float4*)(src + k0 + 36);
    }
    BAR_LGKM();                          // ds_writes visible; global loads in flight
    short8 a = *(const short8*)&As[cur][16*wid + arow][kgrp*8];
    #pragma unroll
    for (int s=0;s<8;s++){
      short8 b = *(const short8*)(wd16 + (size_t)(s*16 + arow)*1024 + k0 + kgrp*8);
      acc[s] = __builtin_amdgcn_mfma_f32_16x16x32_bf16(a, b, acc[s], 0,0,0);
    }
    cur ^= 1;                            // dbuf: no second barrier needed
  }
  #pragma unroll
  for (int s=0;s<8;s++){
    int col = s*16 + arow;
    #pragma unroll
    for (int r=0;r<4;r++){
      int n = n0 + 16*wid + kgrp*4 + r;
      int i = 3*(n>>1) + 1 + (n&1);
      xconv[(size_t)(PREFIX + i)*C_IN + col] = f2b(acc[s][r]);
    }
  }
}

// ---- Y[c][t][o] = xconv[c] @ W_t[:128] + W_t[128+nt[c]]  (bf16 out) ----
__global__ __launch_bounds__(512) void k_y(const ushort* __restrict__ xconv,
    const ushort* __restrict__ w16y, const ushort* __restrict__ wbias,
    const int* __restrict__ ntype, ushort* __restrict__ Y){
  __shared__ ushort As[128*128];    // row*128 + (c16 ^ (row&7))*8
  __shared__ ushort bsh[6272];
  __shared__ int nts[128];
  const int tid = threadIdx.x;
  const int tile = blockIdx.x;

  {
    int row = tid >> 2;
    int c0 = (tid & 3) * 4;
    const ushort* src = xconv + ((size_t)tile*128 + row)*128;
    #pragma unroll
    for (int i=0;i<4;i++){
      int c16 = c0 + i;
      uint4 v = *(const uint4*)(src + c16*8);
      *(uint4*)&As[row*128 + ((c16 ^ (row & 7))*8)] = v;
    }
  }
  for (int i = tid; i < 3136; i += 512) ((uint*)bsh)[i] = ((const uint*)wbias)[i];
  if (tid < 128) nts[tid] = ntype[tile*128 + tid];
  __syncthreads();

  const int w = tid >> 6, l = tid & 63;
  const int mg = w >> 2, nc = w & 3;          // 2 row-groups x 4 col-groups
  const int arow = l & 15, kgrp = l >> 4;
  const int obase = nc*32 + arow;

  for (int t = 0; t < 7; ++t){
    f32x4 acc[4][2];
    #pragma unroll
    for (int mf=0;mf<4;mf++){ acc[mf][0]=(f32x4){0,0,0,0}; acc[mf][1]=(f32x4){0,0,0,0}; }
    const ushort* wt = w16y + t*16384;
    #pragma unroll
    for (int kf = 0; kf < 4; ++kf){
      const int kof = kf*32 + kgrp*8;
      short8 b0 = *(const short8*)(wt + (size_t)obase*128 + kof);
      short8 b1 = *(const short8*)(wt + (size_t)(obase+16)*128 + kof);
      #pragma unroll
      for (int mf = 0; mf < 4; ++mf){
        int row = mg*64 + mf*16 + arow;
        int c16 = (kf*4 + kgrp) ^ (row & 7);
        short8 a = *(const short8*)&As[row*128 + c16*8];
        acc[mf][0] = __builtin_amdgcn_mfma_f32_16x16x32_bf16(a, b0, acc[mf][0], 0,0,0);
        acc[mf][1] = __builtin_amdgcn_mfma_f32_16x16x32_bf16(a, b1, acc[mf][1], 0,0,0);
      }
    }
    #pragma unroll
    for (int mf = 0; mf < 4; ++mf){
      #pragma unroll
      for (int j = 0; j < 4; ++j){
        int rl = mg*64 + mf*16 + (l>>4)*4 + j;
        int ntv = nts[rl];
        size_t grow = ((size_t)(tile*128 + rl)*7 + t)*128;
        int bb = (t*7 + ntv)*128;
        Y[grow + obase]      = f2b(acc[mf][0][j] + b2f_lo((uint)bsh[bb + obase]));
        Y[grow + obase + 16] = f2b(acc[mf][1][j] + b2f_lo((uint)bsh[bb + obase + 16]));
      }
    }
  }
}

// ---- out[v] = sum over bucket[v] of Y rows (f32 accum) ----
__global__ __launch_bounds__(256) void k_gather(const int* __restrict__ cnt,
    const int* __restrict__ bucket, const ushort* __restrict__ Y, float* __restrict__ out){
  const int tid = threadIdx.x;
  const int slot = tid >> 5, lane = tid & 31;
  const int v = blockIdx.x*8 + slot;
  const int n = min(cnt[v], CAP);
  const int* brow = bucket + (size_t)v*CAP;
  float acc[4] = {0.f, 0.f, 0.f, 0.f};

  int m[EG]; uint2 d[EG];
  const int nb = min(n, EG);
  #pragma unroll
  for (int i=0;i<EG;i++) if (i < nb) m[i] = brow[i];
  #pragma unroll
  for (int i=0;i<EG;i++) if (i < nb)
    d[i] = *(const uint2*)(Y + (size_t)m[i]*C_IN + lane*4);
  #pragma unroll
  for (int i=0;i<EG;i++){
    if (i < nb){
      acc[0] += b2f_lo(d[i].x); acc[1] += b2f_hi(d[i].x);
      acc[2] += b2f_lo(d[i].y); acc[3] += b2f_hi(d[i].y);
    }
  }
  for (int e = EG; e < n; e += 4){
    int n4 = min(n - e, 4);
    int m4[4]; uint2 d4[4];
    #pragma unroll
    for (int i=0;i<4;i++) if (i < n4) m4[i] = brow[e + i];
    #pragma unroll
    for (int i=0;i<4;i++) if (i < n4)
      d4[i] = *(const uint2*)(Y + (size_t)m4[i]*C_IN + lane*4);
    #pragma unroll
    for (int i=0;i<4;i++){
      if (i < n4){
        acc[0] += b2f_lo(d4[i].x); acc[1] += b2f_hi(d4[i].x);
        acc[2] += b2f_lo(d4[i].y); acc[3] += b2f_hi(d4[i].y);
      }
    }
  }
  float4 o; o.x = acc[0]; o.y = acc[1]; o.z = acc[2]; o.w = acc[3];
  *(float4*)(out + (size_t)v*C_IN + lane*4) = o;
}

extern "C" void kernel_launch(void* const* d_in, const int* in_sizes, int n_in,
                              void* d_out, int out_size, void* d_ws, size_t ws_size,
                              hipStream_t stream){
  const float* x     = (const float*)d_in[0];
  const int*   ei    = (const int*)d_in[2];
  const int*   et    = (const int*)d_in[3];
  const int*   nt    = (const int*)d_in[4];
  const float* wdown = (const float*)d_in[5];
  const float* wconv = (const float*)d_in[6];
  float* out = (float*)d_out;

  char* p = (char*)d_ws;
  ushort* xconv = (ushort*)p; p += (size_t)N_CONV*C_IN*2;        // 29.36 MB
  ushort* wd16  = (ushort*)p; p += (size_t)128*1024*2;           // 256 KB
  ushort* w16y  = (ushort*)p; p += (size_t)114688*2;             // 224 KB
  ushort* wbias = (ushort*)p; p += 16384;                        // 16 KB
  int* cnt      = (int*)p;    p += (size_t)N_CONV*4;             // 448 KB
  int* bucket   = (int*)p;    p += (size_t)N_CONV*CAP*4;         // 14.68 MB
  ushort* Y     = (ushort*)p;                                    // 205.5 MB

  k_prep<<<COPY_BLK + PREPW_BLK + ZERO_BLK, 256, 0, stream>>>(x, wconv, wdown, xconv, w16y, wbias, wd16, cnt);
  k_sd<<<SCAT_BLK + DOWN_BLK, 256, 0, stream>>>(ei, et, cnt, bucket, x, wd16, xconv);
  k_y<<<N_CONV/128, 512, 0, stream>>>(xconv, w16y, wbias, nt, Y);
  k_gather<<<N_CONV/8, 256, 0, stream>>>(cnt, bucket, Y, out);
}

// Round 8
// 282.891 us; speedup vs baseline: 2.5474x; 1.2840x over previous
//
#include <hip/hip_runtime.h>
#include <stdint.h>

#define C_IN 128
#define NUMD 524288
#define LNUMD 32768
#define NNUM_DM1 (LNUMD + NUMD/8)
#define PREFIX 16384
#define N_CONV (PREFIX + NNUM_DM1)   // 114688
#define N_EDGES (N_CONV * 7)         // 802816
#define ND8 (NUMD/8)                 // 65536
#define CAP 32
#define EG 12

#define COPY_BLK ((PREFIX+LNUMD)*32/256)     // 6144
#define PREPW_N (114688 + 6272 + 131072)     // w16y + wbias + wd16 = 252032
#define PREPW_BLK ((PREPW_N + 255)/256)      // 985
#define ZERO_BLK (N_CONV/1024)               // 112
#define DOWN_BLK (ND8/128)                   // 512
#define SCAT_BLK (N_EDGES/512)               // 1568

typedef __attribute__((ext_vector_type(8))) short short8;
typedef __attribute__((ext_vector_type(4))) float f32x4;

__device__ inline ushort f2b(float f){
  union { float f; uint32_t u; } v; v.f = f;
  uint32_t r = v.u + 0x7fffu + ((v.u >> 16) & 1u);
  return (ushort)(r >> 16);
}
__device__ inline float b2f_lo(uint32_t u){ union { uint32_t u; float f; } v; v.u = u << 16; return v.f; }
__device__ inline float b2f_hi(uint32_t u){ union { uint32_t u; float f; } v; v.u = u & 0xffff0000u; return v.f; }

#define BAR_LGKM() do { \
    asm volatile("s_waitcnt lgkmcnt(0)" ::: "memory"); \
    __builtin_amdgcn_s_barrier(); \
    asm volatile("" ::: "memory"); \
  } while(0)

// ---- fused: copy prefix+leaf rows | weight conversion | zero cnt ----
__global__ void k_prep(const float* __restrict__ x, const float* __restrict__ wconv,
                       const float* __restrict__ wdown,
                       ushort* __restrict__ xconv, ushort* __restrict__ w16y,
                       ushort* __restrict__ wbias, ushort* __restrict__ wd16,
                       int* __restrict__ cnt){
  const int bid = blockIdx.x;
  if (bid < COPY_BLK){
    int gid = bid*256 + threadIdx.x;
    int row = gid >> 5, seg = (gid & 31) * 4;
    int srow, drow;
    if (row < PREFIX){ srow = row; drow = row; }
    else { int k = row - PREFIX; srow = PREFIX + k; drow = PREFIX + 3*k; }
    const float4 f = *(const float4*)(x + (size_t)srow*C_IN + seg);
    ushort4 o; o.x=f2b(f.x); o.y=f2b(f.y); o.z=f2b(f.z); o.w=f2b(f.w);
    *(ushort4*)(xconv + (size_t)drow*C_IN + seg) = o;
  } else if (bid < COPY_BLK + PREPW_BLK){
    int gid = (bid - COPY_BLK)*256 + threadIdx.x;
    if (gid < 114688){
      // w16y[t][o][k] = wconv[(t*135+k)*128 + o]
      int t = gid >> 14, rem = gid & 16383;
      int o = rem >> 7, k = rem & 127;
      w16y[gid] = f2b(wconv[(size_t)(t*135 + k)*128 + o]);
    } else if (gid < 120960){
      // wbias[t][n][o] = wconv[(t*135+128+n)*128 + o]
      int q = gid - 114688;
      int t = q / 896, rem = q % 896;
      int n = rem >> 7, o = rem & 127;
      wbias[q] = f2b(wconv[(size_t)(t*135 + 128 + n)*128 + o]);
    } else if (gid < PREPW_N){
      int i = gid - 120960;
      wd16[i] = f2b(wdown[i]);
    }
  } else {
    int gid = (bid - COPY_BLK - PREPW_BLK)*256 + threadIdx.x;
    int4 z = {0,0,0,0};
    *(int4*)(cnt + gid*4) = z;
  }
}

// ---- fused: down-projection GEMM (128-row tile, K-chunked) | edge scatter ----
__global__ __launch_bounds__(512) void k_sd(const int* __restrict__ ei, const int* __restrict__ et,
    int* __restrict__ cnt, int* __restrict__ bucket,
    const float* __restrict__ x, const ushort* __restrict__ wd16, ushort* __restrict__ xconv){
  const int bid = blockIdx.x;
  if (bid >= DOWN_BLK){
    int e = (bid - DOWN_BLK)*512 + threadIdx.x;
    int r = ei[e], c = ei[N_EDGES + e], t = et[e];
    int pos = atomicAdd(&cnt[r], 1);
    if (pos < CAP) bucket[r*CAP + pos] = c*7 + t;
    return;
  }
  __shared__ ushort As[128*128];      // row*128 + (slot ^ ((row&7)<<1))*8
  const int tid = threadIdx.x;
  const int n0 = bid * 128;
  const float* xd = x + (size_t)(PREFIX+LNUMD)*C_IN;

  const int srow = tid >> 2, kbase = (tid & 3) * 32;
  const float* src = xd + (size_t)(n0+srow)*1024 + kbase;

  const int w = tid >> 6, l = tid & 63;
  const int mg = w >> 2, nc = w & 3;            // 2 row-groups x 4 col-groups
  const int arow = l & 15, kgrp = l >> 4;
  const int obase = nc*32 + arow;

  f32x4 acc[4][2];
  #pragma unroll
  for (int mf=0;mf<4;mf++){ acc[mf][0]=(f32x4){0,0,0,0}; acc[mf][1]=(f32x4){0,0,0,0}; }

  float4 pf[8];
  #pragma unroll
  for (int i=0;i<8;i++) pf[i] = *(const float4*)(src + i*4);

  for (int c = 0; c < 8; ++c){
    // pack prefetched A -> LDS (swizzled)
    #pragma unroll
    for (int i=0;i<4;i++){
      uint4 pk;
      pk.x = (uint)f2b(pf[2*i].x)   | ((uint)f2b(pf[2*i].y)<<16);
      pk.y = (uint)f2b(pf[2*i].z)   | ((uint)f2b(pf[2*i].w)<<16);
      pk.z = (uint)f2b(pf[2*i+1].x) | ((uint)f2b(pf[2*i+1].y)<<16);
      pk.w = (uint)f2b(pf[2*i+1].z) | ((uint)f2b(pf[2*i+1].w)<<16);
      int slot = (kbase >> 3) + i;
      *(uint4*)&As[srow*128 + ((slot ^ ((srow & 7) << 1)) << 3)] = pk;
    }
    BAR_LGKM();                                 // LDS visible; vmcnt untouched

    // B fragments for this chunk -> registers FIRST (oldest in vmcnt FIFO, L2-hot)
    short8 breg[8];
    #pragma unroll
    for (int kf=0;kf<4;kf++){
      const ushort* bp = wd16 + c*128 + kf*32 + kgrp*8;
      breg[kf*2]   = *(const short8*)(bp + (size_t)obase*1024);
      breg[kf*2+1] = *(const short8*)(bp + (size_t)(obase+16)*1024);
    }
    // THEN issue next chunk's A prefetch (youngest: stays in flight over MFMA)
    if (c < 7){
      const float* s2 = src + (c+1)*128;
      #pragma unroll
      for (int i=0;i<8;i++) pf[i] = *(const float4*)(s2 + i*4);
    }

    // MFMA from LDS A + reg B
    #pragma unroll
    for (int kf=0;kf<4;kf++){
      #pragma unroll
      for (int mf=0;mf<4;mf++){
        int row = mg*64 + mf*16 + arow;
        int slot = (kf*4 + kgrp) ^ ((arow & 7) << 1);
        short8 a = *(const short8*)&As[row*128 + (slot << 3)];
        acc[mf][0] = __builtin_amdgcn_mfma_f32_16x16x32_bf16(a, breg[kf*2],   acc[mf][0], 0,0,0);
        acc[mf][1] = __builtin_amdgcn_mfma_f32_16x16x32_bf16(a, breg[kf*2+1], acc[mf][1], 0,0,0);
      }
    }
    BAR_LGKM();                                 // protect As before next ds_write
  }

  #pragma unroll
  for (int mf = 0; mf < 4; ++mf){
    #pragma unroll
    for (int j = 0; j < 4; ++j){
      int rl = mg*64 + mf*16 + (l>>4)*4 + j;
      int n = n0 + rl;
      int i = 3*(n>>1) + 1 + (n&1);
      ushort* dst = xconv + (size_t)(PREFIX + i)*C_IN;
      dst[obase]      = f2b(acc[mf][0][j]);
      dst[obase + 16] = f2b(acc[mf][1][j]);
    }
  }
}

// ---- Y[c][t][o] = xconv[c] @ W_t[:128] + W_t[128+nt[c]]  (bf16 out) ----
__global__ __launch_bounds__(512) void k_y(const ushort* __restrict__ xconv,
    const ushort* __restrict__ w16y, const ushort* __restrict__ wbias,
    const int* __restrict__ ntype, ushort* __restrict__ Y){
  __shared__ ushort As[128*128];    // row*128 + (c16 ^ (row&7))*8
  __shared__ ushort bsh[6272];
  __shared__ int nts[128];
  const int tid = threadIdx.x;
  const int tile = blockIdx.x;

  {
    int row = tid >> 2;
    int c0 = (tid & 3) * 4;
    const ushort* src = xconv + ((size_t)tile*128 + row)*128;
    #pragma unroll
    for (int i=0;i<4;i++){
      int c16 = c0 + i;
      uint4 v = *(const uint4*)(src + c16*8);
      *(uint4*)&As[row*128 + ((c16 ^ (row & 7))*8)] = v;
    }
  }
  for (int i = tid; i < 3136; i += 512) ((uint*)bsh)[i] = ((const uint*)wbias)[i];
  if (tid < 128) nts[tid] = ntype[tile*128 + tid];
  __syncthreads();

  const int w = tid >> 6, l = tid & 63;
  const int mg = w >> 2, nc = w & 3;          // 2 row-groups x 4 col-groups
  const int arow = l & 15, kgrp = l >> 4;
  const int obase = nc*32 + arow;

  for (int t = 0; t < 7; ++t){
    f32x4 acc[4][2];
    #pragma unroll
    for (int mf=0;mf<4;mf++){ acc[mf][0]=(f32x4){0,0,0,0}; acc[mf][1]=(f32x4){0,0,0,0}; }
    const ushort* wt = w16y + t*16384;
    #pragma unroll
    for (int kf = 0; kf < 4; ++kf){
      const int kof = kf*32 + kgrp*8;
      short8 b0 = *(const short8*)(wt + (size_t)obase*128 + kof);
      short8 b1 = *(const short8*)(wt + (size_t)(obase+16)*128 + kof);
      #pragma unroll
      for (int mf = 0; mf < 4; ++mf){
        int row = mg*64 + mf*16 + arow;
        int c16 = (kf*4 + kgrp) ^ (row & 7);
        short8 a = *(const short8*)&As[row*128 + c16*8];
        acc[mf][0] = __builtin_amdgcn_mfma_f32_16x16x32_bf16(a, b0, acc[mf][0], 0,0,0);
        acc[mf][1] = __builtin_amdgcn_mfma_f32_16x16x32_bf16(a, b1, acc[mf][1], 0,0,0);
      }
    }
    #pragma unroll
    for (int mf = 0; mf < 4; ++mf){
      #pragma unroll
      for (int j = 0; j < 4; ++j){
        int rl = mg*64 + mf*16 + (l>>4)*4 + j;
        int ntv = nts[rl];
        size_t grow = ((size_t)(tile*128 + rl)*7 + t)*128;
        int bb = (t*7 + ntv)*128;
        Y[grow + obase]      = f2b(acc[mf][0][j] + b2f_lo((uint)bsh[bb + obase]));
        Y[grow + obase + 16] = f2b(acc[mf][1][j] + b2f_lo((uint)bsh[bb + obase + 16]));
      }
    }
  }
}

// ---- out[v] = sum over bucket[v] of Y rows (f32 accum) ----
__global__ __launch_bounds__(256) void k_gather(const int* __restrict__ cnt,
    const int* __restrict__ bucket, const ushort* __restrict__ Y, float* __restrict__ out){
  const int tid = threadIdx.x;
  const int slot = tid >> 5, lane = tid & 31;
  const int v = blockIdx.x*8 + slot;
  const int n = min(cnt[v], CAP);
  const int* brow = bucket + (size_t)v*CAP;
  float acc[4] = {0.f, 0.f, 0.f, 0.f};

  int m[EG]; uint2 d[EG];
  const int nb = min(n, EG);
  #pragma unroll
  for (int i=0;i<EG;i++) if (i < nb) m[i] = brow[i];
  #pragma unroll
  for (int i=0;i<EG;i++) if (i < nb)
    d[i] = *(const uint2*)(Y + (size_t)m[i]*C_IN + lane*4);
  #pragma unroll
  for (int i=0;i<EG;i++){
    if (i < nb){
      acc[0] += b2f_lo(d[i].x); acc[1] += b2f_hi(d[i].x);
      acc[2] += b2f_lo(d[i].y); acc[3] += b2f_hi(d[i].y);
    }
  }
  for (int e = EG; e < n; e += 4){
    int n4 = min(n - e, 4);
    int m4[4]; uint2 d4[4];
    #pragma unroll
    for (int i=0;i<4;i++) if (i < n4) m4[i] = brow[e + i];
    #pragma unroll
    for (int i=0;i<4;i++) if (i < n4)
      d4[i] = *(const uint2*)(Y + (size_t)m4[i]*C_IN + lane*4);
    #pragma unroll
    for (int i=0;i<4;i++){
      if (i < n4){
        acc[0] += b2f_lo(d4[i].x); acc[1] += b2f_hi(d4[i].x);
        acc[2] += b2f_lo(d4[i].y); acc[3] += b2f_hi(d4[i].y);
      }
    }
  }
  float4 o; o.x = acc[0]; o.y = acc[1]; o.z = acc[2]; o.w = acc[3];
  *(float4*)(out + (size_t)v*C_IN + lane*4) = o;
}

extern "C" void kernel_launch(void* const* d_in, const int* in_sizes, int n_in,
                              void* d_out, int out_size, void* d_ws, size_t ws_size,
                              hipStream_t stream){
  const float* x     = (const float*)d_in[0];
  const int*   ei    = (const int*)d_in[2];
  const int*   et    = (const int*)d_in[3];
  const int*   nt    = (const int*)d_in[4];
  const float* wdown = (const float*)d_in[5];
  const float* wconv = (const float*)d_in[6];
  float* out = (float*)d_out;

  char* p = (char*)d_ws;
  ushort* xconv = (ushort*)p; p += (size_t)N_CONV*C_IN*2;        // 29.36 MB
  ushort* wd16  = (ushort*)p; p += (size_t)128*1024*2;           // 256 KB
  ushort* w16y  = (ushort*)p; p += (size_t)114688*2;             // 224 KB
  ushort* wbias = (ushort*)p; p += 16384;                        // 16 KB
  int* cnt      = (int*)p;    p += (size_t)N_CONV*4;             // 448 KB
  int* bucket   = (int*)p;    p += (size_t)N_CONV*CAP*4;         // 14.68 MB
  ushort* Y     = (ushort*)p;                                    // 205.5 MB

  k_prep<<<COPY_BLK + PREPW_BLK + ZERO_BLK, 256, 0, stream>>>(x, wconv, wdown, xconv, w16y, wbias, wd16, cnt);
  k_sd<<<DOWN_BLK + SCAT_BLK, 512, 0, stream>>>(ei, et, cnt, bucket, x, wd16, xconv);
  k_y<<<N_CONV/128, 512, 0, stream>>>(xconv, w16y, wbias, nt, Y);
  k_gather<<<N_CONV/8, 256, 0, stream>>>(cnt, bucket, Y, out);
}